// Round 1
// baseline (5870.087 us; speedup 1.0000x reference)
//
#include <hip/hip_runtime.h>
#include <cstdint>
#include <cstddef>

constexpr int TPB = 256;

static inline int cdiv(int a, int b) { return (a + b - 1) / b; }

__global__ void deg_init_kernel(float* deg, int n) {
  int i = blockIdx.x * TPB + threadIdx.x;
  if (i < n) deg[i] = 1.0f;
}

__global__ void deg_acc_kernel(const int* __restrict__ dst, float* deg, int e_cnt) {
  int e = blockIdx.x * TPB + threadIdx.x;
  if (e < e_cnt) atomicAdd(&deg[dst[e]], 1.0f);
}

__global__ void rsqrt_kernel(float* deg, int n) {
  int i = blockIdx.x * TPB + threadIdx.x;
  if (i < n) deg[i] = rsqrtf(deg[i]);
}

// out[row][j] = sum_k in[row][k] * W[k][j] (+bias) (+relu)
template<int K, int CO>
__global__ void mm_kernel(const float* __restrict__ in, const float* __restrict__ W,
                          const float* __restrict__ bias, float* __restrict__ out,
                          int n_rows, int do_relu) {
  constexpr int ROWS = 16;
  __shared__ float s_in[ROWS][K];
  int base = blockIdx.x * ROWS;
  for (int i = threadIdx.x; i < ROWS * K; i += TPB) {
    int r = i / K, c = i - r * K;
    int row = base + r;
    s_in[r][c] = (row < n_rows) ? in[(size_t)row * K + c] : 0.0f;
  }
  __syncthreads();
  constexpr int RP = TPB / CO;  // rows computed per pass
  int j = threadIdx.x % CO;
  int sub = threadIdx.x / CO;
  float bj = bias ? bias[j] : 0.0f;
  for (int r = sub; r < ROWS; r += RP) {
    int row = base + r;
    if (row >= n_rows) break;
    float acc = bj;
    #pragma unroll
    for (int k = 0; k < K; ++k) acc = fmaf(s_in[r][k], W[k * CO + j], acc);
    if (do_relu) acc = fmaxf(acc, 0.0f);
    out[(size_t)row * CO + j] = acc;
  }
}

// agg[n][:] = h[n][:] * dinv[n]^2  (self-loop term), float4 over n*32 elems
__global__ void agg_init_kernel(const float4* __restrict__ h, const float* __restrict__ dinv,
                                float4* __restrict__ agg, int total) {
  int i = blockIdx.x * TPB + threadIdx.x;
  if (i >= total) return;
  float di = dinv[i >> 5];
  float s = di * di;
  float4 v = h[i];
  v.x *= s; v.y *= s; v.z *= s; v.w *= s;
  agg[i] = v;
}

// one wave (64 lanes) per edge; 2 features per lane
__global__ void agg_edge_kernel(const int* __restrict__ src, const int* __restrict__ dst,
                                const float* __restrict__ dinv, const float* __restrict__ h,
                                float* __restrict__ agg, int e_cnt) {
  int gid = blockIdx.x * TPB + threadIdx.x;
  int e = gid >> 6;
  int lane = gid & 63;
  if (e >= e_cnt) return;
  int s = src[e], d = dst[e];
  float norm = dinv[s] * dinv[d];
  size_t sb = (size_t)s * 128, db = (size_t)d * 128;
  atomicAdd(&agg[db + lane], h[sb + lane] * norm);
  atomicAdd(&agg[db + 64 + lane], h[sb + 64 + lane] * norm);
}

// in-place: agg = relu(agg + b), float4 over n*32
__global__ void post_kernel(float4* agg, const float* __restrict__ b, int total) {
  int i = blockIdx.x * TPB + threadIdx.x;
  if (i >= total) return;
  int jb = (i & 31) * 4;
  float4 v = agg[i];
  v.x = fmaxf(v.x + b[jb + 0], 0.0f);
  v.y = fmaxf(v.y + b[jb + 1], 0.0f);
  v.z = fmaxf(v.z + b[jb + 2], 0.0f);
  v.w = fmaxf(v.w + b[jb + 3], 0.0f);
  agg[i] = v;
}

// one wave per query; lane j owns Wd2 column j in 128 VGPRs
__global__ __launch_bounds__(256, 2)
void decoder_kernel(const int* __restrict__ qsrc, const int* __restrict__ qdst,
                    const float* __restrict__ atab, const float* __restrict__ btab,
                    const float* __restrict__ Wd2, const float* __restrict__ bd2,
                    const float* __restrict__ Wd3, const float* __restrict__ bd3,
                    float* __restrict__ out, int n_query) {
  int lane = threadIdx.x & 63;
  int wave = (blockIdx.x * TPB + threadIdx.x) >> 6;
  int nwaves = gridDim.x * (TPB / 64);
  float w[128];
  #pragma unroll
  for (int k = 0; k < 128; ++k) w[k] = Wd2[k * 64 + lane];
  float bd2r = bd2[lane];
  float wd3r = Wd3[lane];
  float bd3r = bd3[0];
  for (int q = wave; q < n_query; q += nwaves) {
    int s = qsrc[q], d = qdst[q];
    const float* ap = atab + (size_t)s * 128;
    const float* bp = btab + (size_t)d * 128;
    float d1a = fmaxf(ap[lane] + bp[lane], 0.0f);         // bd1 folded into atab
    float d1b = fmaxf(ap[64 + lane] + bp[64 + lane], 0.0f);
    float acc = 0.0f;
    #pragma unroll
    for (int k = 0; k < 64; ++k) {
      float va = __int_as_float(__builtin_amdgcn_readlane(__float_as_int(d1a), k));
      acc = fmaf(va, w[k], acc);
    }
    #pragma unroll
    for (int k = 0; k < 64; ++k) {
      float vb = __int_as_float(__builtin_amdgcn_readlane(__float_as_int(d1b), k));
      acc = fmaf(vb, w[64 + k], acc);
    }
    float d2 = fmaxf(acc + bd2r, 0.0f);
    float t = d2 * wd3r;
    #pragma unroll
    for (int off = 32; off > 0; off >>= 1) t += __shfl_xor(t, off, 64);
    if (lane == 0) out[q] = 1.0f / (1.0f + expf(-(t + bd3r)));
  }
}

extern "C" void kernel_launch(void* const* d_in, const int* in_sizes, int n_in,
                              void* d_out, int out_size, void* d_ws, size_t ws_size,
                              hipStream_t stream) {
  const float* x    = (const float*)d_in[0];
  const int*   ei   = (const int*)d_in[1];
  const int*   qe   = (const int*)d_in[2];
  const float* W1   = (const float*)d_in[3];
  const float* b1   = (const float*)d_in[4];
  const float* W2   = (const float*)d_in[5];
  const float* b2   = (const float*)d_in[6];
  const float* Wfc  = (const float*)d_in[7];
  const float* bfc  = (const float*)d_in[8];
  const float* Wd1  = (const float*)d_in[9];
  const float* bd1  = (const float*)d_in[10];
  const float* Wd2  = (const float*)d_in[11];
  const float* bd2  = (const float*)d_in[12];
  const float* Wd3  = (const float*)d_in[13];
  const float* bd3  = (const float*)d_in[14];
  float* out = (float*)d_out;

  const int n_nodes = in_sizes[0] / 7;
  const int n_edges = in_sizes[1] / 2;
  const int n_query = in_sizes[2] / 2;
  const int* e_src = ei;
  const int* e_dst = ei + n_edges;
  const int* q_src = qe;
  const int* q_dst = qe + n_query;

  // workspace layout (floats)
  float* ws   = (float*)d_ws;
  float* dinv = ws;                          // n_nodes (deg -> dinv in place)
  float* bufA = ws + 102400;                 // n_nodes*128
  float* bufB = bufA + (size_t)n_nodes * 128;
  float* zbuf = bufB + (size_t)n_nodes * 128;

  const int tot4 = n_nodes * 32;  // float4 count for [n,128] buffers
  const int mm_blocks = cdiv(n_nodes, 16);

  // degree + dinv
  deg_init_kernel<<<cdiv(n_nodes, TPB), TPB, 0, stream>>>(dinv, n_nodes);
  deg_acc_kernel<<<cdiv(n_edges, TPB), TPB, 0, stream>>>(e_dst, dinv, n_edges);
  rsqrt_kernel<<<cdiv(n_nodes, TPB), TPB, 0, stream>>>(dinv, n_nodes);

  // ---- GCN layer 1 ----
  mm_kernel<7, 128><<<mm_blocks, TPB, 0, stream>>>(x, W1, nullptr, bufA, n_nodes, 0);
  agg_init_kernel<<<cdiv(tot4, TPB), TPB, 0, stream>>>((const float4*)bufA, dinv, (float4*)bufB, tot4);
  agg_edge_kernel<<<cdiv(n_edges * 64, TPB), TPB, 0, stream>>>(e_src, e_dst, dinv, bufA, bufB, n_edges);
  post_kernel<<<cdiv(tot4, TPB), TPB, 0, stream>>>((float4*)bufB, b1, tot4);  // h1 in bufB

  // ---- GCN layer 2 ----
  mm_kernel<128, 128><<<mm_blocks, TPB, 0, stream>>>(bufB, W2, nullptr, bufA, n_nodes, 0);
  agg_init_kernel<<<cdiv(tot4, TPB), TPB, 0, stream>>>((const float4*)bufA, dinv, (float4*)bufB, tot4);
  agg_edge_kernel<<<cdiv(n_edges * 64, TPB), TPB, 0, stream>>>(e_src, e_dst, dinv, bufA, bufB, n_edges);
  post_kernel<<<cdiv(tot4, TPB), TPB, 0, stream>>>((float4*)bufB, b2, tot4);  // h2 in bufB

  // ---- encoder fc: z = h2 @ Wfc + bfc ----
  mm_kernel<128, 64><<<mm_blocks, TPB, 0, stream>>>(bufB, Wfc, bfc, zbuf, n_nodes, 0);

  // ---- decoder precompute: a = z@Wd1_top + bd1 ; b = z@Wd1_bot ----
  mm_kernel<64, 128><<<mm_blocks, TPB, 0, stream>>>(zbuf, Wd1, bd1, bufA, n_nodes, 0);
  mm_kernel<64, 128><<<mm_blocks, TPB, 0, stream>>>(zbuf, Wd1 + 64 * 128, nullptr, bufB, n_nodes, 0);

  // ---- per-query decode ----
  decoder_kernel<<<2048, TPB, 0, stream>>>(q_src, q_dst, bufA, bufB, Wd2, bd2, Wd3, bd3, out, n_query);
}

// Round 2
// 2010.062 us; speedup vs baseline: 2.9204x; 2.9204x over previous
//
#include <hip/hip_runtime.h>
#include <cstdint>
#include <cstddef>

constexpr int TPB = 256;

static inline int cdiv(int a, int b) { return (a + b - 1) / b; }

__global__ void deg_init_kernel(float* deg, int n) {
  int i = blockIdx.x * TPB + threadIdx.x;
  if (i < n) deg[i] = 1.0f;
}

__global__ void deg_acc_kernel(const int* __restrict__ dst, float* deg, int e_cnt) {
  int e = blockIdx.x * TPB + threadIdx.x;
  if (e < e_cnt) atomicAdd(&deg[dst[e]], 1.0f);
}

__global__ void rsqrt_kernel(float* deg, int n) {
  int i = blockIdx.x * TPB + threadIdx.x;
  if (i < n) deg[i] = rsqrtf(deg[i]);
}

// Register-tiled SGEMM: out[row][j] = sum_k in[row][k]*W[k][j] (+bias)(+relu)
// BM=64 rows/block, 256 threads as 16(tr) x 16(tc); thread computes TM=4 rows
// x TN=CO/16 cols (cols strided by 16 -> conflict-free LDS reads, coalesced
// stores). W tile staged in LDS (was the R1 bug: per-thread global W reads).
template<int K, int CO>
__global__ __launch_bounds__(256)
void mm_tiled(const float* __restrict__ in, const float* __restrict__ W,
              const float* __restrict__ bias, float* __restrict__ out,
              int n_rows, int do_relu) {
  constexpr int BM = 64;
  constexpr int BK = (K % 32 == 0) ? 32 : K;       // 7 stays 7
  constexpr int SS = BK + 1 + (BK & 1);            // odd stride: 4 tr-groups hit distinct banks
  constexpr int TM = 4;
  constexpr int TN = CO / 16;                      // 8 (CO=128) or 4 (CO=64)
  __shared__ float s_in[BM][SS];
  __shared__ float s_w[BK][CO];
  const int tid = threadIdx.x;
  const int base = blockIdx.x * BM;
  const int tr = tid >> 4;
  const int tc = tid & 15;

  float acc[TM][TN];
  #pragma unroll
  for (int m = 0; m < TM; ++m)
    #pragma unroll
    for (int n = 0; n < TN; ++n) acc[m][n] = 0.0f;

  for (int kb = 0; kb < K; kb += BK) {
    if constexpr (BK % 4 == 0) {
      constexpr int F4 = BM * (BK / 4);
      #pragma unroll
      for (int t = tid; t < F4; t += TPB) {
        int r = t / (BK / 4), c4 = t % (BK / 4);
        int row = base + r;
        float4 v = make_float4(0.f, 0.f, 0.f, 0.f);
        if (row < n_rows) v = *(const float4*)(in + (size_t)row * K + kb + c4 * 4);
        s_in[r][c4 * 4 + 0] = v.x;
        s_in[r][c4 * 4 + 1] = v.y;
        s_in[r][c4 * 4 + 2] = v.z;
        s_in[r][c4 * 4 + 3] = v.w;
      }
      constexpr int WF4 = BK * CO / 4;
      #pragma unroll
      for (int t = tid; t < WF4; t += TPB)
        *(float4*)(&s_w[0][0] + t * 4) = *(const float4*)(W + (size_t)kb * CO + t * 4);
    } else {
      for (int t = tid; t < BM * BK; t += TPB) {
        int r = t / BK, c = t % BK;
        int row = base + r;
        s_in[r][c] = (row < n_rows) ? in[(size_t)row * K + kb + c] : 0.0f;
      }
      for (int t = tid; t < BK * CO; t += TPB)
        (&s_w[0][0])[t] = W[(size_t)kb * CO + t];
    }
    __syncthreads();

    #pragma unroll
    for (int kk = 0; kk < BK; ++kk) {
      float a[TM], b[TN];
      #pragma unroll
      for (int m = 0; m < TM; ++m) a[m] = s_in[tr * TM + m][kk];
      #pragma unroll
      for (int n = 0; n < TN; ++n) b[n] = s_w[kk][tc + 16 * n];
      #pragma unroll
      for (int m = 0; m < TM; ++m)
        #pragma unroll
        for (int n = 0; n < TN; ++n) acc[m][n] = fmaf(a[m], b[n], acc[m][n]);
    }
    __syncthreads();
  }

  #pragma unroll
  for (int m = 0; m < TM; ++m) {
    int row = base + tr * TM + m;
    if (row < n_rows) {
      #pragma unroll
      for (int n = 0; n < TN; ++n) {
        int j = tc + 16 * n;
        float v = acc[m][n] + (bias ? bias[j] : 0.0f);
        if (do_relu) v = fmaxf(v, 0.0f);
        out[(size_t)row * CO + j] = v;
      }
    }
  }
}

// agg[n][:] = h[n][:] * dinv[n]^2  (self-loop term), float4 over n*32 elems
__global__ void agg_init_kernel(const float4* __restrict__ h, const float* __restrict__ dinv,
                                float4* __restrict__ agg, int total) {
  int i = blockIdx.x * TPB + threadIdx.x;
  if (i >= total) return;
  float di = dinv[i >> 5];
  float s = di * di;
  float4 v = h[i];
  v.x *= s; v.y *= s; v.z *= s; v.w *= s;
  agg[i] = v;
}

// one wave (64 lanes) per edge; 2 features per lane
__global__ void agg_edge_kernel(const int* __restrict__ src, const int* __restrict__ dst,
                                const float* __restrict__ dinv, const float* __restrict__ h,
                                float* __restrict__ agg, int e_cnt) {
  int gid = blockIdx.x * TPB + threadIdx.x;
  int e = gid >> 6;
  int lane = gid & 63;
  if (e >= e_cnt) return;
  int s = src[e], d = dst[e];
  float norm = dinv[s] * dinv[d];
  size_t sb = (size_t)s * 128, db = (size_t)d * 128;
  atomicAdd(&agg[db + lane], h[sb + lane] * norm);
  atomicAdd(&agg[db + 64 + lane], h[sb + 64 + lane] * norm);
}

// in-place: agg = relu(agg + b), float4 over n*32
__global__ void post_kernel(float4* agg, const float* __restrict__ b, int total) {
  int i = blockIdx.x * TPB + threadIdx.x;
  if (i >= total) return;
  int jb = (i & 31) * 4;
  float4 v = agg[i];
  v.x = fmaxf(v.x + b[jb + 0], 0.0f);
  v.y = fmaxf(v.y + b[jb + 1], 0.0f);
  v.z = fmaxf(v.z + b[jb + 2], 0.0f);
  v.w = fmaxf(v.w + b[jb + 3], 0.0f);
  agg[i] = v;
}

// one wave per query; lane j owns Wd2 column j in 128 VGPRs
__global__ __launch_bounds__(256, 2)
void decoder_kernel(const int* __restrict__ qsrc, const int* __restrict__ qdst,
                    const float* __restrict__ atab, const float* __restrict__ btab,
                    const float* __restrict__ Wd2, const float* __restrict__ bd2,
                    const float* __restrict__ Wd3, const float* __restrict__ bd3,
                    float* __restrict__ out, int n_query) {
  int lane = threadIdx.x & 63;
  int wave = (blockIdx.x * TPB + threadIdx.x) >> 6;
  int nwaves = gridDim.x * (TPB / 64);
  float w[128];
  #pragma unroll
  for (int k = 0; k < 128; ++k) w[k] = Wd2[k * 64 + lane];
  float bd2r = bd2[lane];
  float wd3r = Wd3[lane];
  float bd3r = bd3[0];
  for (int q = wave; q < n_query; q += nwaves) {
    int s = qsrc[q], d = qdst[q];
    const float* ap = atab + (size_t)s * 128;
    const float* bp = btab + (size_t)d * 128;
    float d1a = fmaxf(ap[lane] + bp[lane], 0.0f);         // bd1 folded into atab
    float d1b = fmaxf(ap[64 + lane] + bp[64 + lane], 0.0f);
    float acc = 0.0f;
    #pragma unroll
    for (int k = 0; k < 64; ++k) {
      float va = __int_as_float(__builtin_amdgcn_readlane(__float_as_int(d1a), k));
      acc = fmaf(va, w[k], acc);
    }
    #pragma unroll
    for (int k = 0; k < 64; ++k) {
      float vb = __int_as_float(__builtin_amdgcn_readlane(__float_as_int(d1b), k));
      acc = fmaf(vb, w[64 + k], acc);
    }
    float d2 = fmaxf(acc + bd2r, 0.0f);
    float t = d2 * wd3r;
    #pragma unroll
    for (int off = 32; off > 0; off >>= 1) t += __shfl_xor(t, off, 64);
    if (lane == 0) out[q] = 1.0f / (1.0f + expf(-(t + bd3r)));
  }
}

extern "C" void kernel_launch(void* const* d_in, const int* in_sizes, int n_in,
                              void* d_out, int out_size, void* d_ws, size_t ws_size,
                              hipStream_t stream) {
  const float* x    = (const float*)d_in[0];
  const int*   ei   = (const int*)d_in[1];
  const int*   qe   = (const int*)d_in[2];
  const float* W1   = (const float*)d_in[3];
  const float* b1   = (const float*)d_in[4];
  const float* W2   = (const float*)d_in[5];
  const float* b2   = (const float*)d_in[6];
  const float* Wfc  = (const float*)d_in[7];
  const float* bfc  = (const float*)d_in[8];
  const float* Wd1  = (const float*)d_in[9];
  const float* bd1  = (const float*)d_in[10];
  const float* Wd2  = (const float*)d_in[11];
  const float* bd2  = (const float*)d_in[12];
  const float* Wd3  = (const float*)d_in[13];
  const float* bd3  = (const float*)d_in[14];
  float* out = (float*)d_out;

  const int n_nodes = in_sizes[0] / 7;
  const int n_edges = in_sizes[1] / 2;
  const int n_query = in_sizes[2] / 2;
  const int* e_src = ei;
  const int* e_dst = ei + n_edges;
  const int* q_src = qe;
  const int* q_dst = qe + n_query;

  // workspace layout (floats)
  float* ws   = (float*)d_ws;
  float* dinv = ws;                          // n_nodes (deg -> dinv in place)
  float* bufA = ws + 102400;                 // n_nodes*128
  float* bufB = bufA + (size_t)n_nodes * 128;
  float* zbuf = bufB + (size_t)n_nodes * 128;

  const int tot4 = n_nodes * 32;  // float4 count for [n,128] buffers
  const int mm_blocks = cdiv(n_nodes, 64);

  // degree + dinv
  deg_init_kernel<<<cdiv(n_nodes, TPB), TPB, 0, stream>>>(dinv, n_nodes);
  deg_acc_kernel<<<cdiv(n_edges, TPB), TPB, 0, stream>>>(e_dst, dinv, n_edges);
  rsqrt_kernel<<<cdiv(n_nodes, TPB), TPB, 0, stream>>>(dinv, n_nodes);

  // ---- GCN layer 1 ----
  mm_tiled<7, 128><<<mm_blocks, TPB, 0, stream>>>(x, W1, nullptr, bufA, n_nodes, 0);
  agg_init_kernel<<<cdiv(tot4, TPB), TPB, 0, stream>>>((const float4*)bufA, dinv, (float4*)bufB, tot4);
  agg_edge_kernel<<<cdiv(n_edges * 64, TPB), TPB, 0, stream>>>(e_src, e_dst, dinv, bufA, bufB, n_edges);
  post_kernel<<<cdiv(tot4, TPB), TPB, 0, stream>>>((float4*)bufB, b1, tot4);  // h1 in bufB

  // ---- GCN layer 2 ----
  mm_tiled<128, 128><<<mm_blocks, TPB, 0, stream>>>(bufB, W2, nullptr, bufA, n_nodes, 0);
  agg_init_kernel<<<cdiv(tot4, TPB), TPB, 0, stream>>>((const float4*)bufA, dinv, (float4*)bufB, tot4);
  agg_edge_kernel<<<cdiv(n_edges * 64, TPB), TPB, 0, stream>>>(e_src, e_dst, dinv, bufA, bufB, n_edges);
  post_kernel<<<cdiv(tot4, TPB), TPB, 0, stream>>>((float4*)bufB, b2, tot4);  // h2 in bufB

  // ---- encoder fc: z = h2 @ Wfc + bfc ----
  mm_tiled<128, 64><<<mm_blocks, TPB, 0, stream>>>(bufB, Wfc, bfc, zbuf, n_nodes, 0);

  // ---- decoder precompute: a = z@Wd1_top + bd1 ; b = z@Wd1_bot ----
  mm_tiled<64, 128><<<mm_blocks, TPB, 0, stream>>>(zbuf, Wd1, bd1, bufA, n_nodes, 0);
  mm_tiled<64, 128><<<mm_blocks, TPB, 0, stream>>>(zbuf, Wd1 + 64 * 128, nullptr, bufB, n_nodes, 0);

  // ---- per-query decode ----
  decoder_kernel<<<2048, TPB, 0, stream>>>(q_src, q_dst, bufA, bufB, Wd2, bd2, Wd3, bd3, out, n_query);
}

// Round 3
// 1223.484 us; speedup vs baseline: 4.7978x; 1.6429x over previous
//
#include <hip/hip_runtime.h>
#include <cstdint>
#include <cstddef>

constexpr int TPB = 256;

static inline int cdiv(int a, int b) { return (a + b - 1) / b; }

__global__ void zero_int_kernel(int* p, int n) {
  int i = blockIdx.x * TPB + threadIdx.x;
  if (i < n) p[i] = 0;
}

__global__ void hist_kernel(const int* __restrict__ dst, int* counts, int e_cnt) {
  int e = blockIdx.x * TPB + threadIdx.x;
  if (e < e_cnt) atomicAdd(&counts[dst[e]], 1);
}

__global__ void dinv_kernel(const int* __restrict__ counts, float* dinv, int n) {
  int i = blockIdx.x * TPB + threadIdx.x;
  if (i < n) dinv[i] = rsqrtf((float)counts[i] + 1.0f);  // +1 self-loop
}

// single-block exclusive scan: counts[0..n) -> rowptr[0..n]
__global__ void scan_kernel(const int* __restrict__ counts, int* rowptr, int n, int total) {
  constexpr int S = 1024;
  __shared__ int s[S];
  __shared__ int carry_s;
  int tid = threadIdx.x;
  if (tid == 0) carry_s = 0;
  __syncthreads();
  for (int base = 0; base < n; base += S) {
    int i = base + tid;
    int v = (i < n) ? counts[i] : 0;
    s[tid] = v;
    __syncthreads();
    #pragma unroll
    for (int off = 1; off < S; off <<= 1) {
      int t = (tid >= off) ? s[tid - off] : 0;
      __syncthreads();
      s[tid] += t;
      __syncthreads();
    }
    int incl = s[tid];
    int c = carry_s;
    if (i < n) rowptr[i] = c + incl - v;
    __syncthreads();
    if (tid == S - 1) carry_s = c + incl;
    __syncthreads();
  }
  if (tid == 0) rowptr[n] = total;
}

__global__ void scatter_kernel(const int* __restrict__ src, const int* __restrict__ dst,
                               const int* __restrict__ rowptr, int* cursor,
                               int* __restrict__ csr_src, int e_cnt) {
  int e = blockIdx.x * TPB + threadIdx.x;
  if (e >= e_cnt) return;
  int d = dst[e];
  int pos = rowptr[d] + atomicAdd(&cursor[d], 1);
  csr_src[pos] = src[e];
}

// Register-tiled SGEMM: out[row][j] = sum_k in[row][k]*W[k][j] (+bias)(+relu)
template<int K, int CO>
__global__ __launch_bounds__(256)
void mm_tiled(const float* __restrict__ in, const float* __restrict__ W,
              const float* __restrict__ bias, float* __restrict__ out,
              int n_rows, int do_relu) {
  constexpr int BM = 64;
  constexpr int BK = (K % 32 == 0) ? 32 : K;
  constexpr int SS = BK + 1 + (BK & 1);
  constexpr int TM = 4;
  constexpr int TN = CO / 16;
  __shared__ float s_in[BM][SS];
  __shared__ float s_w[BK][CO];
  const int tid = threadIdx.x;
  const int base = blockIdx.x * BM;
  const int tr = tid >> 4;
  const int tc = tid & 15;

  float acc[TM][TN];
  #pragma unroll
  for (int m = 0; m < TM; ++m)
    #pragma unroll
    for (int n = 0; n < TN; ++n) acc[m][n] = 0.0f;

  for (int kb = 0; kb < K; kb += BK) {
    if constexpr (BK % 4 == 0) {
      constexpr int F4 = BM * (BK / 4);
      #pragma unroll
      for (int t = tid; t < F4; t += TPB) {
        int r = t / (BK / 4), c4 = t % (BK / 4);
        int row = base + r;
        float4 v = make_float4(0.f, 0.f, 0.f, 0.f);
        if (row < n_rows) v = *(const float4*)(in + (size_t)row * K + kb + c4 * 4);
        s_in[r][c4 * 4 + 0] = v.x;
        s_in[r][c4 * 4 + 1] = v.y;
        s_in[r][c4 * 4 + 2] = v.z;
        s_in[r][c4 * 4 + 3] = v.w;
      }
      constexpr int WF4 = BK * CO / 4;
      #pragma unroll
      for (int t = tid; t < WF4; t += TPB)
        *(float4*)(&s_w[0][0] + t * 4) = *(const float4*)(W + (size_t)kb * CO + t * 4);
    } else {
      for (int t = tid; t < BM * BK; t += TPB) {
        int r = t / BK, c = t % BK;
        int row = base + r;
        s_in[r][c] = (row < n_rows) ? in[(size_t)row * K + kb + c] : 0.0f;
      }
      for (int t = tid; t < BK * CO; t += TPB)
        (&s_w[0][0])[t] = W[(size_t)kb * CO + t];
    }
    __syncthreads();

    #pragma unroll
    for (int kk = 0; kk < BK; ++kk) {
      float a[TM], b[TN];
      #pragma unroll
      for (int m = 0; m < TM; ++m) a[m] = s_in[tr * TM + m][kk];
      #pragma unroll
      for (int n = 0; n < TN; ++n) b[n] = s_w[kk][tc + 16 * n];
      #pragma unroll
      for (int m = 0; m < TM; ++m)
        #pragma unroll
        for (int n = 0; n < TN; ++n) acc[m][n] = fmaf(a[m], b[n], acc[m][n]);
    }
    __syncthreads();
  }

  #pragma unroll
  for (int m = 0; m < TM; ++m) {
    int row = base + tr * TM + m;
    if (row < n_rows) {
      #pragma unroll
      for (int n = 0; n < TN; ++n) {
        int j = tc + 16 * n;
        float v = acc[m][n] + (bias ? bias[j] : 0.0f);
        if (do_relu) v = fmaxf(v, 0.0f);
        out[(size_t)row * CO + j] = v;
      }
    }
  }
}

// Fused GCN aggregation: one wave per node, float2 (2 feats) per lane.
// out[n] = relu( h[n]*dinv[n]^2 + sum_{s in N(n)} h[s]*dinv[s]*dinv[n] + bias )
__global__ __launch_bounds__(256)
void gcn_gather_kernel(const int* __restrict__ rowptr, const int* __restrict__ csr_src,
                       const float* __restrict__ dinv, const float* __restrict__ h,
                       const float* __restrict__ bias, float* __restrict__ out, int n_nodes) {
  int wid = (blockIdx.x * TPB + threadIdx.x) >> 6;
  int lane = threadIdx.x & 63;
  if (wid >= n_nodes) return;
  const float2* h2 = (const float2*)h;
  float dn = dinv[wid];
  float2 v = h2[(size_t)wid * 64 + lane];
  float2 acc = make_float2(v.x * dn * dn, v.y * dn * dn);
  int beg = rowptr[wid], end = rowptr[wid + 1];
  for (int i = beg; i < end; ++i) {
    int s = __builtin_amdgcn_readfirstlane(csr_src[i]);
    float norm = dinv[s] * dn;
    float2 hv = h2[(size_t)s * 64 + lane];
    acc.x = fmaf(hv.x, norm, acc.x);
    acc.y = fmaf(hv.y, norm, acc.y);
  }
  float2 bv = ((const float2*)bias)[lane];
  acc.x = fmaxf(acc.x + bv.x, 0.0f);
  acc.y = fmaxf(acc.y + bv.y, 0.0f);
  ((float2*)out)[(size_t)wid * 64 + lane] = acc;
}

// one wave per query; lane j owns Wd2 column j in 128 VGPRs
__global__ __launch_bounds__(256, 2)
void decoder_kernel(const int* __restrict__ qsrc, const int* __restrict__ qdst,
                    const float* __restrict__ atab, const float* __restrict__ btab,
                    const float* __restrict__ Wd2, const float* __restrict__ bd2,
                    const float* __restrict__ Wd3, const float* __restrict__ bd3,
                    float* __restrict__ out, int n_query) {
  int lane = threadIdx.x & 63;
  int wave = (blockIdx.x * TPB + threadIdx.x) >> 6;
  int nwaves = gridDim.x * (TPB / 64);
  float w[128];
  #pragma unroll
  for (int k = 0; k < 128; ++k) w[k] = Wd2[k * 64 + lane];
  float bd2r = bd2[lane];
  float wd3r = Wd3[lane];
  float bd3r = bd3[0];
  for (int q = wave; q < n_query; q += nwaves) {
    int s = qsrc[q], d = qdst[q];
    const float* ap = atab + (size_t)s * 128;
    const float* bp = btab + (size_t)d * 128;
    float d1a = fmaxf(ap[lane] + bp[lane], 0.0f);         // bd1 folded into atab
    float d1b = fmaxf(ap[64 + lane] + bp[64 + lane], 0.0f);
    float acc = 0.0f;
    #pragma unroll
    for (int k = 0; k < 64; ++k) {
      float va = __int_as_float(__builtin_amdgcn_readlane(__float_as_int(d1a), k));
      acc = fmaf(va, w[k], acc);
    }
    #pragma unroll
    for (int k = 0; k < 64; ++k) {
      float vb = __int_as_float(__builtin_amdgcn_readlane(__float_as_int(d1b), k));
      acc = fmaf(vb, w[64 + k], acc);
    }
    float d2 = fmaxf(acc + bd2r, 0.0f);
    float t = d2 * wd3r;
    #pragma unroll
    for (int off = 32; off > 0; off >>= 1) t += __shfl_xor(t, off, 64);
    if (lane == 0) out[q] = 1.0f / (1.0f + expf(-(t + bd3r)));
  }
}

extern "C" void kernel_launch(void* const* d_in, const int* in_sizes, int n_in,
                              void* d_out, int out_size, void* d_ws, size_t ws_size,
                              hipStream_t stream) {
  const float* x    = (const float*)d_in[0];
  const int*   ei   = (const int*)d_in[1];
  const int*   qe   = (const int*)d_in[2];
  const float* W1   = (const float*)d_in[3];
  const float* b1   = (const float*)d_in[4];
  const float* W2   = (const float*)d_in[5];
  const float* b2   = (const float*)d_in[6];
  const float* Wfc  = (const float*)d_in[7];
  const float* bfc  = (const float*)d_in[8];
  const float* Wd1  = (const float*)d_in[9];
  const float* bd1  = (const float*)d_in[10];
  const float* Wd2  = (const float*)d_in[11];
  const float* bd2  = (const float*)d_in[12];
  const float* Wd3  = (const float*)d_in[13];
  const float* bd3  = (const float*)d_in[14];
  float* out = (float*)d_out;

  const int n_nodes = in_sizes[0] / 7;
  const int n_edges = in_sizes[1] / 2;
  const int n_query = in_sizes[2] / 2;
  const int* e_src = ei;
  const int* e_dst = ei + n_edges;
  const int* q_src = qe;
  const int* q_dst = qe + n_query;

  // ---- workspace layout ----
  char* wp = (char*)d_ws;
  auto take = [&](size_t bytes) { char* p = wp; wp += (bytes + 255) & ~size_t(255); return p; };
  float* dinv    = (float*)take((size_t)n_nodes * 4);
  int*   counts  = (int*)  take((size_t)n_nodes * 4);   // reused as cursor
  int*   rowptr  = (int*)  take((size_t)(n_nodes + 1) * 4);
  int*   csr_src = (int*)  take((size_t)n_edges * 4);
  float* bufP    = (float*)take((size_t)n_nodes * 128 * 4);
  float* bufQ    = (float*)take((size_t)n_nodes * 128 * 4);
  float* bufR    = (float*)take((size_t)n_nodes * 64 * 4);

  const int mm_blocks = cdiv(n_nodes, 64);
  const int node_blocks = cdiv(n_nodes, TPB);
  const int edge_blocks = cdiv(n_edges, TPB);
  const int gather_blocks = cdiv(n_nodes * 64, TPB);

  // ---- CSR build (dst-major) + dinv ----
  zero_int_kernel<<<node_blocks, TPB, 0, stream>>>(counts, n_nodes);
  hist_kernel<<<edge_blocks, TPB, 0, stream>>>(e_dst, counts, n_edges);
  dinv_kernel<<<node_blocks, TPB, 0, stream>>>(counts, dinv, n_nodes);
  scan_kernel<<<1, 1024, 0, stream>>>(counts, rowptr, n_nodes, n_edges);
  zero_int_kernel<<<node_blocks, TPB, 0, stream>>>(counts, n_nodes);  // -> cursor
  scatter_kernel<<<edge_blocks, TPB, 0, stream>>>(e_src, e_dst, rowptr, counts, csr_src, n_edges);

  // ---- GCN layer 1: P = x@W1 ; Q = relu(agg(P) + b1) ----
  mm_tiled<7, 128><<<mm_blocks, TPB, 0, stream>>>(x, W1, nullptr, bufP, n_nodes, 0);
  gcn_gather_kernel<<<gather_blocks, TPB, 0, stream>>>(rowptr, csr_src, dinv, bufP, b1, bufQ, n_nodes);

  // ---- GCN layer 2: P = Q@W2 ; Q = relu(agg(P) + b2) ----
  mm_tiled<128, 128><<<mm_blocks, TPB, 0, stream>>>(bufQ, W2, nullptr, bufP, n_nodes, 0);
  gcn_gather_kernel<<<gather_blocks, TPB, 0, stream>>>(rowptr, csr_src, dinv, bufP, b2, bufQ, n_nodes);

  // ---- encoder fc: R = Q@Wfc + bfc ----
  mm_tiled<128, 64><<<mm_blocks, TPB, 0, stream>>>(bufQ, Wfc, bfc, bufR, n_nodes, 0);

  // ---- decoder precompute: P = R@Wd1_top + bd1 ; Q = R@Wd1_bot ----
  mm_tiled<64, 128><<<mm_blocks, TPB, 0, stream>>>(bufR, Wd1, bd1, bufP, n_nodes, 0);
  mm_tiled<64, 128><<<mm_blocks, TPB, 0, stream>>>(bufR, Wd1 + 64 * 128, nullptr, bufQ, n_nodes, 0);

  // ---- per-query decode ----
  decoder_kernel<<<2048, TPB, 0, stream>>>(q_src, q_dst, bufP, bufQ, Wd2, bd2, Wd3, bd3, out, n_query);
}

// Round 4
// 834.701 us; speedup vs baseline: 7.0326x; 1.4658x over previous
//
#include <hip/hip_runtime.h>
#include <hip/hip_bf16.h>
#include <cstdint>
#include <cstddef>

constexpr int TPB = 256;
using bf16x8 = __attribute__((ext_vector_type(8))) short;
using f32x4  = __attribute__((ext_vector_type(4))) float;

static inline int cdiv(int a, int b) { return (a + b - 1) / b; }

__device__ __forceinline__ float bf2f(short u) {
  return __uint_as_float(((unsigned int)(unsigned short)u) << 16);
}
__device__ __forceinline__ short f2bf(float f) {  // RNE
  unsigned int u = __float_as_uint(f);
  return (short)((u + 0x7FFF + ((u >> 16) & 1)) >> 16);
}

__global__ void zero_int_kernel(int* p, int n) {
  int i = blockIdx.x * TPB + threadIdx.x;
  if (i < n) p[i] = 0;
}

__global__ void hist_kernel(const int* __restrict__ dst, int* counts, int e_cnt) {
  int e = blockIdx.x * TPB + threadIdx.x;
  if (e < e_cnt) atomicAdd(&counts[dst[e]], 1);
}

__global__ void dinv_kernel(const int* __restrict__ counts, float* dinv, int n) {
  int i = blockIdx.x * TPB + threadIdx.x;
  if (i < n) dinv[i] = rsqrtf((float)counts[i] + 1.0f);  // +1 self-loop
}

// single-block exclusive scan, shuffle-based (few barriers)
__global__ void scan_kernel(const int* __restrict__ counts, int* __restrict__ rowptr,
                            int n, int total) {
  __shared__ int wsum[16];
  __shared__ int carry_s;
  const int tid = threadIdx.x;
  const int lane = tid & 63;
  const int w = tid >> 6;
  if (tid == 0) carry_s = 0;
  __syncthreads();
  for (int base = 0; base < n; base += 1024) {
    int i = base + tid;
    int v = (i < n) ? counts[i] : 0;
    int s = v;
    #pragma unroll
    for (int off = 1; off < 64; off <<= 1) {
      int t = __shfl_up(s, off, 64);
      if (lane >= off) s += t;
    }
    if (lane == 63) wsum[w] = s;
    __syncthreads();
    if (tid < 16) {
      int ws_ = wsum[tid];
      #pragma unroll
      for (int off = 1; off < 16; off <<= 1) {
        int t = __shfl_up(ws_, off, 64);
        if (tid >= off) ws_ += t;
      }
      wsum[tid] = ws_;
    }
    __syncthreads();
    int c = carry_s;
    int woff = (w == 0) ? 0 : wsum[w - 1];
    if (i < n) rowptr[i] = c + woff + s - v;
    __syncthreads();
    if (tid == 0) carry_s = c + wsum[15];
    __syncthreads();
  }
  if (tid == 0) rowptr[n] = total;
}

__global__ void scatter_kernel(const int* __restrict__ src, const int* __restrict__ dst,
                               const int* __restrict__ rowptr, int* cursor,
                               int* __restrict__ csr_src, int e_cnt) {
  int e = blockIdx.x * TPB + threadIdx.x;
  if (e >= e_cnt) return;
  int d = dst[e];
  int pos = rowptr[d] + atomicAdd(&cursor[d], 1);
  csr_src[pos] = src[e];
}

// Register-tiled SGEMM: out[row][j] = sum_k in[row][k]*W[k][j] (+bias)(+relu)
// OB: store output as bf16 (for decoder tables)
template<int K, int CO, bool OB>
__global__ __launch_bounds__(256)
void mm_tiled(const float* __restrict__ in, const float* __restrict__ W,
              const float* __restrict__ bias, void* __restrict__ outv,
              int n_rows, int do_relu) {
  constexpr int BM = 64;
  constexpr int BK = (K % 32 == 0) ? 32 : K;
  constexpr int SS = BK + 1 + (BK & 1);
  constexpr int TM = 4;
  constexpr int TN = CO / 16;
  __shared__ float s_in[BM][SS];
  __shared__ float s_w[BK][CO];
  const int tid = threadIdx.x;
  const int base = blockIdx.x * BM;
  const int tr = tid >> 4;
  const int tc = tid & 15;

  float acc[TM][TN];
  #pragma unroll
  for (int m = 0; m < TM; ++m)
    #pragma unroll
    for (int n = 0; n < TN; ++n) acc[m][n] = 0.0f;

  for (int kb = 0; kb < K; kb += BK) {
    if constexpr (BK % 4 == 0) {
      constexpr int F4 = BM * (BK / 4);
      #pragma unroll
      for (int t = tid; t < F4; t += TPB) {
        int r = t / (BK / 4), c4 = t % (BK / 4);
        int row = base + r;
        float4 v = make_float4(0.f, 0.f, 0.f, 0.f);
        if (row < n_rows) v = *(const float4*)(in + (size_t)row * K + kb + c4 * 4);
        s_in[r][c4 * 4 + 0] = v.x;
        s_in[r][c4 * 4 + 1] = v.y;
        s_in[r][c4 * 4 + 2] = v.z;
        s_in[r][c4 * 4 + 3] = v.w;
      }
      constexpr int WF4 = BK * CO / 4;
      #pragma unroll
      for (int t = tid; t < WF4; t += TPB)
        *(float4*)(&s_w[0][0] + t * 4) = *(const float4*)(W + (size_t)kb * CO + t * 4);
    } else {
      for (int t = tid; t < BM * BK; t += TPB) {
        int r = t / BK, c = t % BK;
        int row = base + r;
        s_in[r][c] = (row < n_rows) ? in[(size_t)row * K + kb + c] : 0.0f;
      }
      for (int t = tid; t < BK * CO; t += TPB)
        (&s_w[0][0])[t] = W[(size_t)kb * CO + t];
    }
    __syncthreads();

    #pragma unroll
    for (int kk = 0; kk < BK; ++kk) {
      float a[TM], b[TN];
      #pragma unroll
      for (int m = 0; m < TM; ++m) a[m] = s_in[tr * TM + m][kk];
      #pragma unroll
      for (int n = 0; n < TN; ++n) b[n] = s_w[kk][tc + 16 * n];
      #pragma unroll
      for (int m = 0; m < TM; ++m)
        #pragma unroll
        for (int n = 0; n < TN; ++n) acc[m][n] = fmaf(a[m], b[n], acc[m][n]);
    }
    __syncthreads();
  }

  #pragma unroll
  for (int m = 0; m < TM; ++m) {
    int row = base + tr * TM + m;
    if (row < n_rows) {
      #pragma unroll
      for (int n = 0; n < TN; ++n) {
        int j = tc + 16 * n;
        float v = acc[m][n] + (bias ? bias[j] : 0.0f);
        if (do_relu) v = fmaxf(v, 0.0f);
        if constexpr (OB)
          ((unsigned short*)outv)[(size_t)row * CO + j] = (unsigned short)f2bf(v);
        else
          ((float*)outv)[(size_t)row * CO + j] = v;
      }
    }
  }
}

// Fused GCN aggregation: one wave per node, float2 (2 feats) per lane.
__global__ __launch_bounds__(256)
void gcn_gather_kernel(const int* __restrict__ rowptr, const int* __restrict__ csr_src,
                       const float* __restrict__ dinv, const float* __restrict__ h,
                       const float* __restrict__ bias, float* __restrict__ out, int n_nodes) {
  int wid = (blockIdx.x * TPB + threadIdx.x) >> 6;
  int lane = threadIdx.x & 63;
  if (wid >= n_nodes) return;
  const float2* h2 = (const float2*)h;
  float dn = dinv[wid];
  float2 v = h2[(size_t)wid * 64 + lane];
  float2 acc = make_float2(v.x * dn * dn, v.y * dn * dn);
  int beg = rowptr[wid], end = rowptr[wid + 1];
  for (int i = beg; i < end; ++i) {
    int s = __builtin_amdgcn_readfirstlane(csr_src[i]);
    float norm = dinv[s] * dn;
    float2 hv = h2[(size_t)s * 64 + lane];
    acc.x = fmaf(hv.x, norm, acc.x);
    acc.y = fmaf(hv.y, norm, acc.y);
  }
  float2 bv = ((const float2*)bias)[lane];
  acc.x = fmaxf(acc.x + bv.x, 0.0f);
  acc.y = fmaxf(acc.y + bv.y, 0.0f);
  ((float2*)out)[(size_t)wid * 64 + lane] = acc;
}

// MFMA decoder: 16 queries per wave-tile.
// A-frag (d1, 16x32 per k-step): row=lane&15 (query), k=(lane>>4)*8+j
// B-frag (Wd2, 32x16):          col=lane&15,         k=(lane>>4)*8+j
// C/D: col=lane&15, row=(lane>>4)*4+reg  (guide-verified)
__global__ __launch_bounds__(256)
void decoder_mfma_kernel(const int* __restrict__ qsrc, const int* __restrict__ qdst,
                         const unsigned short* __restrict__ atab,
                         const unsigned short* __restrict__ btab,
                         const float* __restrict__ Wd2, const float* __restrict__ bd2,
                         const float* __restrict__ Wd3, const float* __restrict__ bd3,
                         float* __restrict__ out, int n_query) {
  const int lane = threadIdx.x & 63;
  const int col = lane & 15;
  const int sub = lane >> 4;

  // Wd2 -> bf16 B-fragments, once per wave
  bf16x8 bfrag[4][4];
  #pragma unroll
  for (int ks = 0; ks < 4; ++ks)
    #pragma unroll
    for (int nt = 0; nt < 4; ++nt) {
      bf16x8 f;
      #pragma unroll
      for (int j = 0; j < 8; ++j) {
        int k = ks * 32 + sub * 8 + j;
        int n = nt * 16 + col;
        f[j] = f2bf(Wd2[k * 64 + n]);
      }
      bfrag[ks][nt] = f;
    }
  float bd2v[4], wd3v[4];
  #pragma unroll
  for (int nt = 0; nt < 4; ++nt) {
    bd2v[nt] = bd2[nt * 16 + col];
    wd3v[nt] = Wd3[nt * 16 + col];
  }
  const float bd3s = bd3[0];

  int wave = (blockIdx.x * TPB + threadIdx.x) >> 6;
  int nwaves = gridDim.x * (TPB / 64);
  int ntiles = (n_query + 15) >> 4;
  for (int t = wave; t < ntiles; t += nwaves) {
    int qb = t << 4;
    int q = qb + col;
    if (q >= n_query) q = n_query - 1;
    int si = qsrc[q], di = qdst[q];
    const bf16x8* ar = (const bf16x8*)(atab + (size_t)si * 128);
    const bf16x8* br = (const bf16x8*)(btab + (size_t)di * 128);
    bf16x8 afrag[4];
    #pragma unroll
    for (int ks = 0; ks < 4; ++ks) {
      bf16x8 av = ar[ks * 4 + sub];
      bf16x8 bv = br[ks * 4 + sub];
      bf16x8 d;
      #pragma unroll
      for (int j = 0; j < 8; ++j)
        d[j] = f2bf(fmaxf(bf2f(av[j]) + bf2f(bv[j]), 0.0f));  // d1 = relu(a+b)
      afrag[ks] = d;
    }
    f32x4 acc[4];
    #pragma unroll
    for (int nt = 0; nt < 4; ++nt) acc[nt] = {0.f, 0.f, 0.f, 0.f};
    #pragma unroll
    for (int ks = 0; ks < 4; ++ks)
      #pragma unroll
      for (int nt = 0; nt < 4; ++nt)
        acc[nt] = __builtin_amdgcn_mfma_f32_16x16x32_bf16(afrag[ks], bfrag[ks][nt], acc[nt], 0, 0, 0);
    float part[4] = {0.f, 0.f, 0.f, 0.f};
    #pragma unroll
    for (int nt = 0; nt < 4; ++nt)
      #pragma unroll
      for (int r = 0; r < 4; ++r) {
        float v = fmaxf(acc[nt][r] + bd2v[nt], 0.0f);       // d2
        part[r] = fmaf(v, wd3v[nt], part[r]);               // * Wd3
      }
    #pragma unroll
    for (int off = 1; off < 16; off <<= 1)
      #pragma unroll
      for (int r = 0; r < 4; ++r) part[r] += __shfl_xor(part[r], off, 64);
    if (col == 0) {
      int row0 = qb + sub * 4;
      #pragma unroll
      for (int r = 0; r < 4; ++r) {
        int qq = row0 + r;
        if (qq < n_query) out[qq] = 1.0f / (1.0f + __expf(-(part[r] + bd3s)));
      }
    }
  }
}

extern "C" void kernel_launch(void* const* d_in, const int* in_sizes, int n_in,
                              void* d_out, int out_size, void* d_ws, size_t ws_size,
                              hipStream_t stream) {
  const float* x    = (const float*)d_in[0];
  const int*   ei   = (const int*)d_in[1];
  const int*   qe   = (const int*)d_in[2];
  const float* W1   = (const float*)d_in[3];
  const float* b1   = (const float*)d_in[4];
  const float* W2   = (const float*)d_in[5];
  const float* b2   = (const float*)d_in[6];
  const float* Wfc  = (const float*)d_in[7];
  const float* bfc  = (const float*)d_in[8];
  const float* Wd1  = (const float*)d_in[9];
  const float* bd1  = (const float*)d_in[10];
  const float* Wd2  = (const float*)d_in[11];
  const float* bd2  = (const float*)d_in[12];
  const float* Wd3  = (const float*)d_in[13];
  const float* bd3  = (const float*)d_in[14];
  float* out = (float*)d_out;

  const int n_nodes = in_sizes[0] / 7;
  const int n_edges = in_sizes[1] / 2;
  const int n_query = in_sizes[2] / 2;
  const int* e_src = ei;
  const int* e_dst = ei + n_edges;
  const int* q_src = qe;
  const int* q_dst = qe + n_query;

  // ---- workspace layout ----
  char* wp = (char*)d_ws;
  auto take = [&](size_t bytes) { char* p = wp; wp += (bytes + 255) & ~size_t(255); return p; };
  float* dinv    = (float*)take((size_t)n_nodes * 4);
  int*   counts  = (int*)  take((size_t)n_nodes * 4);   // reused as cursor
  int*   rowptr  = (int*)  take((size_t)(n_nodes + 1) * 4);
  int*   csr_src = (int*)  take((size_t)n_edges * 4);
  float* bufP    = (float*)take((size_t)n_nodes * 128 * 4);
  float* bufQ    = (float*)take((size_t)n_nodes * 128 * 4);
  float* bufR    = (float*)take((size_t)n_nodes * 64 * 4);
  // bf16 decoder tables alias bufP/bufQ (free after encoder fc)
  unsigned short* atab = (unsigned short*)bufP;
  unsigned short* btab = (unsigned short*)bufQ;

  const int mm_blocks = cdiv(n_nodes, 64);
  const int node_blocks = cdiv(n_nodes, TPB);
  const int edge_blocks = cdiv(n_edges, TPB);
  const int gather_blocks = cdiv(n_nodes * 64, TPB);

  // ---- CSR build (dst-major) + dinv ----
  zero_int_kernel<<<node_blocks, TPB, 0, stream>>>(counts, n_nodes);
  hist_kernel<<<edge_blocks, TPB, 0, stream>>>(e_dst, counts, n_edges);
  dinv_kernel<<<node_blocks, TPB, 0, stream>>>(counts, dinv, n_nodes);
  scan_kernel<<<1, 1024, 0, stream>>>(counts, rowptr, n_nodes, n_edges);
  zero_int_kernel<<<node_blocks, TPB, 0, stream>>>(counts, n_nodes);  // -> cursor
  scatter_kernel<<<edge_blocks, TPB, 0, stream>>>(e_src, e_dst, rowptr, counts, csr_src, n_edges);

  // ---- GCN layer 1: P = x@W1 ; Q = relu(agg(P) + b1) ----
  mm_tiled<7, 128, false><<<mm_blocks, TPB, 0, stream>>>(x, W1, nullptr, bufP, n_nodes, 0);
  gcn_gather_kernel<<<gather_blocks, TPB, 0, stream>>>(rowptr, csr_src, dinv, bufP, b1, bufQ, n_nodes);

  // ---- GCN layer 2: P = Q@W2 ; Q = relu(agg(P) + b2) ----
  mm_tiled<128, 128, false><<<mm_blocks, TPB, 0, stream>>>(bufQ, W2, nullptr, bufP, n_nodes, 0);
  gcn_gather_kernel<<<gather_blocks, TPB, 0, stream>>>(rowptr, csr_src, dinv, bufP, b2, bufQ, n_nodes);

  // ---- encoder fc: R = Q@Wfc + bfc ----
  mm_tiled<128, 64, false><<<mm_blocks, TPB, 0, stream>>>(bufQ, Wfc, bfc, bufR, n_nodes, 0);

  // ---- decoder precompute (bf16 tables): atab = R@Wd1_top + bd1 ; btab = R@Wd1_bot ----
  mm_tiled<64, 128, true><<<mm_blocks, TPB, 0, stream>>>(bufR, Wd1, bd1, atab, n_nodes, 0);
  mm_tiled<64, 128, true><<<mm_blocks, TPB, 0, stream>>>(bufR, Wd1 + 64 * 128, nullptr, btab, n_nodes, 0);

  // ---- per-query decode (MFMA) ----
  decoder_mfma_kernel<<<1024, TPB, 0, stream>>>(q_src, q_dst, atab, btab, Wd2, bd2, Wd3, bd3, out, n_query);
}

// Round 5
// 601.256 us; speedup vs baseline: 9.7630x; 1.3883x over previous
//
#include <hip/hip_runtime.h>
#include <hip/hip_bf16.h>
#include <cstdint>
#include <cstddef>

constexpr int TPB = 256;
constexpr int SCAN_B = 1024;
using bf16x8 = __attribute__((ext_vector_type(8))) short;
using f32x4  = __attribute__((ext_vector_type(4))) float;

static inline int cdiv(int a, int b) { return (a + b - 1) / b; }

__device__ __forceinline__ float bf2f(short u) {
  return __uint_as_float(((unsigned int)(unsigned short)u) << 16);
}
__device__ __forceinline__ short f2bf(float f) {  // RNE
  unsigned int u = __float_as_uint(f);
  return (short)((u + 0x7FFF + ((u >> 16) & 1)) >> 16);
}

__global__ void zero_int_kernel(int* p, int n) {
  int i = blockIdx.x * TPB + threadIdx.x;
  if (i < n) p[i] = 0;
}

__global__ void hist_kernel(const int* __restrict__ dst, int* counts, int e_cnt) {
  int e = blockIdx.x * TPB + threadIdx.x;
  if (e < e_cnt) atomicAdd(&counts[dst[e]], 1);
}

__global__ void dinv_kernel(const int* __restrict__ counts, float* dinv, int n) {
  int i = blockIdx.x * TPB + threadIdx.x;
  if (i < n) dinv[i] = rsqrtf((float)counts[i] + 1.0f);  // +1 self-loop
}

// multi-block scan, phase 1: per-block exclusive scan + block sums
__global__ __launch_bounds__(SCAN_B)
void scan_block_kernel(const int* __restrict__ counts, int* __restrict__ rowptr,
                       int* __restrict__ bsum, int n) {
  __shared__ int wsum[16];
  const int tid = threadIdx.x;
  const int i = blockIdx.x * SCAN_B + tid;
  const int lane = tid & 63;
  const int w = tid >> 6;
  int v = (i < n) ? counts[i] : 0;
  int s = v;
  #pragma unroll
  for (int off = 1; off < 64; off <<= 1) {
    int t = __shfl_up(s, off, 64);
    if (lane >= off) s += t;
  }
  if (lane == 63) wsum[w] = s;
  __syncthreads();
  if (tid < 16) {
    int ws_ = wsum[tid];
    #pragma unroll
    for (int off = 1; off < 16; off <<= 1) {
      int t = __shfl_up(ws_, off, 64);
      if (tid >= off) ws_ += t;
    }
    wsum[tid] = ws_;
  }
  __syncthreads();
  int woff = (w == 0) ? 0 : wsum[w - 1];
  if (i < n) rowptr[i] = woff + s - v;
  if (tid == SCAN_B - 1) bsum[blockIdx.x] = woff + s;
}

// phase 2: exclusive scan of block sums (nb <= 128), one block of 128
__global__ void scan_carry_kernel(int* bsum, int nb) {
  __shared__ int w0;
  int tid = threadIdx.x;
  int v = (tid < nb) ? bsum[tid] : 0;
  int s = v;
  #pragma unroll
  for (int off = 1; off < 64; off <<= 1) {
    int t = __shfl_up(s, off, 64);
    if ((tid & 63) >= off) s += t;
  }
  if (tid == 63) w0 = s;
  __syncthreads();
  int incl = s + ((tid >= 64) ? w0 : 0);
  if (tid < nb) bsum[tid] = incl - v;
}

// phase 3: add block offsets
__global__ void scan_add_kernel(int* rowptr, const int* __restrict__ bsum, int n, int total) {
  int i = blockIdx.x * TPB + threadIdx.x;
  if (i < n) rowptr[i] += bsum[i / SCAN_B];
  if (i == 0) rowptr[n] = total;
}

__global__ void scatter_kernel(const int* __restrict__ src, const int* __restrict__ dst,
                               const int* __restrict__ rowptr, int* cursor,
                               int* __restrict__ csr_src, int e_cnt) {
  int e = blockIdx.x * TPB + threadIdx.x;
  if (e >= e_cnt) return;
  int d = dst[e];
  int pos = rowptr[d] + atomicAdd(&cursor[d], 1);
  csr_src[pos] = src[e];
}

// pad x [n,7] -> x8 [n,8] (8th = 0)
__global__ void pad_x8_kernel(const float* __restrict__ x, float* __restrict__ x8, int n) {
  int i = blockIdx.x * TPB + threadIdx.x;
  if (i >= n * 8) return;
  int node = i >> 3, f = i & 7;
  x8[i] = (f < 7) ? x[node * 7 + f] : 0.0f;
}

// pad W1 [7,128] -> W1p [8,128]
__global__ void pad_w1_kernel(const float* __restrict__ W1, float* __restrict__ W1p) {
  int i = blockIdx.x * TPB + threadIdx.x;
  if (i < 8 * 128) W1p[i] = (i < 7 * 128) ? W1[i] : 0.0f;
}

// aggx = A_hat @ x8 : 8 lanes per node (one float each)
__global__ __launch_bounds__(256)
void agg_x_kernel(const int* __restrict__ rowptr, const int* __restrict__ csr_src,
                  const float* __restrict__ dinv, const float* __restrict__ x8,
                  float* __restrict__ aggx, int n_nodes) {
  int gid = blockIdx.x * TPB + threadIdx.x;
  int node = gid >> 3;
  int f = gid & 7;
  if (node >= n_nodes) return;
  float dn = dinv[node];
  float acc = x8[(size_t)node * 8 + f] * dn * dn;
  int beg = rowptr[node], end = rowptr[node + 1];
  for (int i = beg; i < end; ++i) {
    int s = csr_src[i];
    acc = fmaf(x8[(size_t)s * 8 + f], dinv[s] * dn, acc);
  }
  aggx[(size_t)node * 8 + f] = acc;
}

// g1 = A_hat @ h1 (h1 in bf16, [n,128]); one wave per node, uint=2xbf16 per lane
__global__ __launch_bounds__(256)
void gather_bf16_kernel(const int* __restrict__ rowptr, const int* __restrict__ csr_src,
                        const float* __restrict__ dinv, const unsigned int* __restrict__ h1b,
                        float* __restrict__ g1, int n_nodes) {
  int wid = (blockIdx.x * TPB + threadIdx.x) >> 6;
  int lane = threadIdx.x & 63;
  if (wid >= n_nodes) return;
  float dn = dinv[wid];
  unsigned int hv = h1b[(size_t)wid * 64 + lane];
  float lo = __uint_as_float(hv << 16);
  float hi = __uint_as_float(hv & 0xffff0000u);
  float ax = lo * dn * dn, ay = hi * dn * dn;
  int beg = rowptr[wid], end = rowptr[wid + 1];
  for (int i = beg; i < end; ++i) {
    int s = __builtin_amdgcn_readfirstlane(csr_src[i]);
    float norm = dinv[s] * dn;
    unsigned int v = h1b[(size_t)s * 64 + lane];
    ax = fmaf(__uint_as_float(v << 16), norm, ax);
    ay = fmaf(__uint_as_float(v & 0xffff0000u), norm, ay);
  }
  ((float2*)g1)[(size_t)wid * 64 + lane] = make_float2(ax, ay);
}

// Register-tiled SGEMM: out[row][j] = sum_k in[row][k]*W[k][j] (+bias)(+relu)
// OB: store output as bf16
template<int K, int CO, bool OB>
__global__ __launch_bounds__(256)
void mm_tiled(const float* __restrict__ in, const float* __restrict__ W,
              const float* __restrict__ bias, void* __restrict__ outv,
              int n_rows, int do_relu) {
  constexpr int BM = 64;
  constexpr int BK = (K % 32 == 0) ? 32 : K;
  constexpr int SS = BK + 1 + (BK & 1);
  constexpr int TM = 4;
  constexpr int TN = CO / 16;
  __shared__ float s_in[BM][SS];
  __shared__ float s_w[BK][CO];
  const int tid = threadIdx.x;
  const int base = blockIdx.x * BM;
  const int tr = tid >> 4;
  const int tc = tid & 15;

  float acc[TM][TN];
  #pragma unroll
  for (int m = 0; m < TM; ++m)
    #pragma unroll
    for (int n = 0; n < TN; ++n) acc[m][n] = 0.0f;

  for (int kb = 0; kb < K; kb += BK) {
    if constexpr (BK % 4 == 0) {
      constexpr int F4 = BM * (BK / 4);
      #pragma unroll
      for (int t = tid; t < F4; t += TPB) {
        int r = t / (BK / 4), c4 = t % (BK / 4);
        int row = base + r;
        float4 v = make_float4(0.f, 0.f, 0.f, 0.f);
        if (row < n_rows) v = *(const float4*)(in + (size_t)row * K + kb + c4 * 4);
        s_in[r][c4 * 4 + 0] = v.x;
        s_in[r][c4 * 4 + 1] = v.y;
        s_in[r][c4 * 4 + 2] = v.z;
        s_in[r][c4 * 4 + 3] = v.w;
      }
      constexpr int WF4 = BK * CO / 4;
      #pragma unroll
      for (int t = tid; t < WF4; t += TPB)
        *(float4*)(&s_w[0][0] + t * 4) = *(const float4*)(W + (size_t)kb * CO + t * 4);
    } else {
      for (int t = tid; t < BM * BK; t += TPB) {
        int r = t / BK, c = t % BK;
        int row = base + r;
        s_in[r][c] = (row < n_rows) ? in[(size_t)row * K + kb + c] : 0.0f;
      }
      for (int t = tid; t < BK * CO; t += TPB)
        (&s_w[0][0])[t] = W[(size_t)kb * CO + t];
    }
    __syncthreads();

    #pragma unroll
    for (int kk = 0; kk < BK; ++kk) {
      float a[TM], b[TN];
      #pragma unroll
      for (int m = 0; m < TM; ++m) a[m] = s_in[tr * TM + m][kk];
      #pragma unroll
      for (int n = 0; n < TN; ++n) b[n] = s_w[kk][tc + 16 * n];
      #pragma unroll
      for (int m = 0; m < TM; ++m)
        #pragma unroll
        for (int n = 0; n < TN; ++n) acc[m][n] = fmaf(a[m], b[n], acc[m][n]);
    }
    __syncthreads();
  }

  #pragma unroll
  for (int m = 0; m < TM; ++m) {
    int row = base + tr * TM + m;
    if (row < n_rows) {
      #pragma unroll
      for (int n = 0; n < TN; ++n) {
        int j = tc + 16 * n;
        float v = acc[m][n] + (bias ? bias[j] : 0.0f);
        if (do_relu) v = fmaxf(v, 0.0f);
        if constexpr (OB)
          ((unsigned short*)outv)[(size_t)row * CO + j] = (unsigned short)f2bf(v);
        else
          ((float*)outv)[(size_t)row * CO + j] = v;
      }
    }
  }
}

// MFMA decoder: 16 queries per wave-tile. (layouts guide-verified)
__global__ __launch_bounds__(256)
void decoder_mfma_kernel(const int* __restrict__ qsrc, const int* __restrict__ qdst,
                         const unsigned short* __restrict__ atab,
                         const unsigned short* __restrict__ btab,
                         const float* __restrict__ Wd2, const float* __restrict__ bd2,
                         const float* __restrict__ Wd3, const float* __restrict__ bd3,
                         float* __restrict__ out, int n_query) {
  const int lane = threadIdx.x & 63;
  const int col = lane & 15;
  const int sub = lane >> 4;

  bf16x8 bfrag[4][4];
  #pragma unroll
  for (int ks = 0; ks < 4; ++ks)
    #pragma unroll
    for (int nt = 0; nt < 4; ++nt) {
      bf16x8 f;
      #pragma unroll
      for (int j = 0; j < 8; ++j) {
        int k = ks * 32 + sub * 8 + j;
        int n = nt * 16 + col;
        f[j] = f2bf(Wd2[k * 64 + n]);
      }
      bfrag[ks][nt] = f;
    }
  float bd2v[4], wd3v[4];
  #pragma unroll
  for (int nt = 0; nt < 4; ++nt) {
    bd2v[nt] = bd2[nt * 16 + col];
    wd3v[nt] = Wd3[nt * 16 + col];
  }
  const float bd3s = bd3[0];

  int wave = (blockIdx.x * TPB + threadIdx.x) >> 6;
  int nwaves = gridDim.x * (TPB / 64);
  int ntiles = (n_query + 15) >> 4;
  for (int t = wave; t < ntiles; t += nwaves) {
    int qb = t << 4;
    int q = qb + col;
    if (q >= n_query) q = n_query - 1;
    int si = qsrc[q], di = qdst[q];
    const bf16x8* ar = (const bf16x8*)(atab + (size_t)si * 128);
    const bf16x8* br = (const bf16x8*)(btab + (size_t)di * 128);
    bf16x8 afrag[4];
    #pragma unroll
    for (int ks = 0; ks < 4; ++ks) {
      bf16x8 av = ar[ks * 4 + sub];
      bf16x8 bv = br[ks * 4 + sub];
      bf16x8 d;
      #pragma unroll
      for (int j = 0; j < 8; ++j)
        d[j] = f2bf(fmaxf(bf2f(av[j]) + bf2f(bv[j]), 0.0f));  // d1 = relu(a+b)
      afrag[ks] = d;
    }
    f32x4 acc[4];
    #pragma unroll
    for (int nt = 0; nt < 4; ++nt) acc[nt] = {0.f, 0.f, 0.f, 0.f};
    #pragma unroll
    for (int ks = 0; ks < 4; ++ks)
      #pragma unroll
      for (int nt = 0; nt < 4; ++nt)
        acc[nt] = __builtin_amdgcn_mfma_f32_16x16x32_bf16(afrag[ks], bfrag[ks][nt], acc[nt], 0, 0, 0);
    float part[4] = {0.f, 0.f, 0.f, 0.f};
    #pragma unroll
    for (int nt = 0; nt < 4; ++nt)
      #pragma unroll
      for (int r = 0; r < 4; ++r) {
        float v = fmaxf(acc[nt][r] + bd2v[nt], 0.0f);
        part[r] = fmaf(v, wd3v[nt], part[r]);
      }
    #pragma unroll
    for (int off = 1; off < 16; off <<= 1)
      #pragma unroll
      for (int r = 0; r < 4; ++r) part[r] += __shfl_xor(part[r], off, 64);
    if (col == 0) {
      int row0 = qb + sub * 4;
      #pragma unroll
      for (int r = 0; r < 4; ++r) {
        int qq = row0 + r;
        if (qq < n_query) out[qq] = 1.0f / (1.0f + __expf(-(part[r] + bd3s)));
      }
    }
  }
}

extern "C" void kernel_launch(void* const* d_in, const int* in_sizes, int n_in,
                              void* d_out, int out_size, void* d_ws, size_t ws_size,
                              hipStream_t stream) {
  const float* x    = (const float*)d_in[0];
  const int*   ei   = (const int*)d_in[1];
  const int*   qe   = (const int*)d_in[2];
  const float* W1   = (const float*)d_in[3];
  const float* b1   = (const float*)d_in[4];
  const float* W2   = (const float*)d_in[5];
  const float* b2   = (const float*)d_in[6];
  const float* Wfc  = (const float*)d_in[7];
  const float* bfc  = (const float*)d_in[8];
  const float* Wd1  = (const float*)d_in[9];
  const float* bd1  = (const float*)d_in[10];
  const float* Wd2  = (const float*)d_in[11];
  const float* bd2  = (const float*)d_in[12];
  const float* Wd3  = (const float*)d_in[13];
  const float* bd3  = (const float*)d_in[14];
  float* out = (float*)d_out;

  const int n_nodes = in_sizes[0] / 7;
  const int n_edges = in_sizes[1] / 2;
  const int n_query = in_sizes[2] / 2;
  const int* e_src = ei;
  const int* e_dst = ei + n_edges;
  const int* q_src = qe;
  const int* q_dst = qe + n_query;

  // ---- workspace layout ----
  char* wp = (char*)d_ws;
  auto take = [&](size_t bytes) { char* p = wp; wp += (bytes + 255) & ~size_t(255); return p; };
  float* dinv    = (float*)take((size_t)n_nodes * 4);
  int*   counts  = (int*)  take((size_t)n_nodes * 4);   // reused as cursor
  int*   rowptr  = (int*)  take((size_t)(n_nodes + 1) * 4);
  int*   bsum    = (int*)  take(512 * 4);
  int*   csr_src = (int*)  take((size_t)n_edges * 4);
  float* x8      = (float*)take((size_t)n_nodes * 8 * 4);
  float* aggx    = (float*)take((size_t)n_nodes * 8 * 4);
  float* W1p     = (float*)take(8 * 128 * 4);
  float* bufP    = (float*)take((size_t)n_nodes * 128 * 4);
  float* bufQ    = (float*)take((size_t)n_nodes * 128 * 4);
  float* bufR    = (float*)take((size_t)n_nodes * 64 * 4);

  const int mm_blocks = cdiv(n_nodes, 64);
  const int node_blocks = cdiv(n_nodes, TPB);
  const int edge_blocks = cdiv(n_edges, TPB);
  const int scan_blocks = cdiv(n_nodes, SCAN_B);

  // ---- CSR build (dst-major) + dinv ----
  zero_int_kernel<<<node_blocks, TPB, 0, stream>>>(counts, n_nodes);
  hist_kernel<<<edge_blocks, TPB, 0, stream>>>(e_dst, counts, n_edges);
  dinv_kernel<<<node_blocks, TPB, 0, stream>>>(counts, dinv, n_nodes);
  scan_block_kernel<<<scan_blocks, SCAN_B, 0, stream>>>(counts, rowptr, bsum, n_nodes);
  scan_carry_kernel<<<1, 128, 0, stream>>>(bsum, scan_blocks);
  scan_add_kernel<<<node_blocks, TPB, 0, stream>>>(rowptr, bsum, n_nodes, n_edges);
  zero_int_kernel<<<node_blocks, TPB, 0, stream>>>(counts, n_nodes);  // -> cursor
  scatter_kernel<<<edge_blocks, TPB, 0, stream>>>(e_src, e_dst, rowptr, counts, csr_src, n_edges);

  // ---- pad x / W1 ----
  pad_x8_kernel<<<cdiv(n_nodes * 8, TPB), TPB, 0, stream>>>(x, x8, n_nodes);
  pad_w1_kernel<<<4, TPB, 0, stream>>>(W1, W1p);

  // ---- layer 1: aggx = A_hat x ; h1(bf16) = relu(aggx @ W1p + b1) ----
  agg_x_kernel<<<cdiv(n_nodes * 8, TPB), TPB, 0, stream>>>(rowptr, csr_src, dinv, x8, aggx, n_nodes);
  mm_tiled<8, 128, true><<<mm_blocks, TPB, 0, stream>>>(aggx, W1p, b1, bufP, n_nodes, 1);
  // bufP now holds h1 as bf16 [n,128]

  // ---- layer 2: g1 = A_hat h1 ; h2 = relu(g1 @ W2 + b2) ----
  gather_bf16_kernel<<<cdiv(n_nodes * 64, TPB), TPB, 0, stream>>>(rowptr, csr_src, dinv,
                                                                  (const unsigned int*)bufP, bufQ, n_nodes);
  mm_tiled<128, 128, false><<<mm_blocks, TPB, 0, stream>>>(bufQ, W2, b2, bufP, n_nodes, 1);
  // bufP = h2 (f32)

  // ---- encoder fc: z = h2 @ Wfc + bfc ----
  mm_tiled<128, 64, false><<<mm_blocks, TPB, 0, stream>>>(bufP, Wfc, bfc, bufR, n_nodes, 0);

  // ---- decoder tables (bf16): atab = z@Wd1_top + bd1 -> bufQ ; btab = z@Wd1_bot -> bufP ----
  unsigned short* atab = (unsigned short*)bufQ;
  unsigned short* btab = (unsigned short*)bufP;
  mm_tiled<64, 128, true><<<mm_blocks, TPB, 0, stream>>>(bufR, Wd1, bd1, atab, n_nodes, 0);
  mm_tiled<64, 128, true><<<mm_blocks, TPB, 0, stream>>>(bufR, Wd1 + 64 * 128, nullptr, btab, n_nodes, 0);

  // ---- per-query decode (MFMA) ----
  decoder_mfma_kernel<<<1024, TPB, 0, stream>>>(q_src, q_dst, atab, btab, Wd2, bd2, Wd3, bd3, out, n_query);
}

// Round 6
// 522.596 us; speedup vs baseline: 11.2326x; 1.1505x over previous
//
#include <hip/hip_runtime.h>
#include <hip/hip_bf16.h>
#include <cstdint>
#include <cstddef>

constexpr int TPB = 256;
constexpr int SCAN_B = 1024;
using bf16x8 = __attribute__((ext_vector_type(8))) short;
using f32x4  = __attribute__((ext_vector_type(4))) float;

static inline int cdiv(int a, int b) { return (a + b - 1) / b; }

__device__ __forceinline__ float bf2f(short u) {
  return __uint_as_float(((unsigned int)(unsigned short)u) << 16);
}
__device__ __forceinline__ short f2bf(float f) {  // RNE
  unsigned int u = __float_as_uint(f);
  return (short)((u + 0x7FFF + ((u >> 16) & 1)) >> 16);
}

__global__ void zero_int_kernel(int* p, int n) {
  int i = blockIdx.x * TPB + threadIdx.x;
  if (i < n) p[i] = 0;
}

__global__ void hist_kernel(const int* __restrict__ dst, int* counts, int e_cnt) {
  int e = blockIdx.x * TPB + threadIdx.x;
  if (e < e_cnt) atomicAdd(&counts[dst[e]], 1);
}

__global__ void dinv_kernel(const int* __restrict__ counts, float* dinv, int n) {
  int i = blockIdx.x * TPB + threadIdx.x;
  if (i < n) dinv[i] = rsqrtf((float)counts[i] + 1.0f);  // +1 self-loop
}

// multi-block scan, phase 1: per-block exclusive scan + block sums
__global__ __launch_bounds__(SCAN_B)
void scan_block_kernel(const int* __restrict__ counts, int* __restrict__ rowptr,
                       int* __restrict__ bsum, int n) {
  __shared__ int wsum[16];
  const int tid = threadIdx.x;
  const int i = blockIdx.x * SCAN_B + tid;
  const int lane = tid & 63;
  const int w = tid >> 6;
  int v = (i < n) ? counts[i] : 0;
  int s = v;
  #pragma unroll
  for (int off = 1; off < 64; off <<= 1) {
    int t = __shfl_up(s, off, 64);
    if (lane >= off) s += t;
  }
  if (lane == 63) wsum[w] = s;
  __syncthreads();
  if (tid < 16) {
    int ws_ = wsum[tid];
    #pragma unroll
    for (int off = 1; off < 16; off <<= 1) {
      int t = __shfl_up(ws_, off, 64);
      if (tid >= off) ws_ += t;
    }
    wsum[tid] = ws_;
  }
  __syncthreads();
  int woff = (w == 0) ? 0 : wsum[w - 1];
  if (i < n) rowptr[i] = woff + s - v;
  if (tid == SCAN_B - 1) bsum[blockIdx.x] = woff + s;
}

// phase 2: exclusive scan of block sums (nb <= 128), one block of 128
__global__ void scan_carry_kernel(int* bsum, int nb) {
  __shared__ int w0;
  int tid = threadIdx.x;
  int v = (tid < nb) ? bsum[tid] : 0;
  int s = v;
  #pragma unroll
  for (int off = 1; off < 64; off <<= 1) {
    int t = __shfl_up(s, off, 64);
    if ((tid & 63) >= off) s += t;
  }
  if (tid == 63) w0 = s;
  __syncthreads();
  int incl = s + ((tid >= 64) ? w0 : 0);
  if (tid < nb) bsum[tid] = incl - v;
}

// phase 3: add block offsets
__global__ void scan_add_kernel(int* rowptr, const int* __restrict__ bsum, int n, int total) {
  int i = blockIdx.x * TPB + threadIdx.x;
  if (i < n) rowptr[i] += bsum[i / SCAN_B];
  if (i == 0) rowptr[n] = total;
}

__global__ void scatter_kernel(const int* __restrict__ src, const int* __restrict__ dst,
                               const int* __restrict__ rowptr, int* cursor,
                               int* __restrict__ csr_src, int e_cnt) {
  int e = blockIdx.x * TPB + threadIdx.x;
  if (e >= e_cnt) return;
  int d = dst[e];
  int pos = rowptr[d] + atomicAdd(&cursor[d], 1);
  csr_src[pos] = src[e];
}

// pad x [n,7] -> x8 [n,8] (8th = 0)
__global__ void pad_x8_kernel(const float* __restrict__ x, float* __restrict__ x8, int n) {
  int i = blockIdx.x * TPB + threadIdx.x;
  if (i >= n * 8) return;
  int node = i >> 3, f = i & 7;
  x8[i] = (f < 7) ? x[node * 7 + f] : 0.0f;
}

// pad W1 [7,128] -> W1p [8,128]
__global__ void pad_w1_kernel(const float* __restrict__ W1, float* __restrict__ W1p) {
  int i = blockIdx.x * TPB + threadIdx.x;
  if (i < 8 * 128) W1p[i] = (i < 7 * 128) ? W1[i] : 0.0f;
}

// aggx = A_hat @ x8 : 8 lanes per node (one float each)
__global__ __launch_bounds__(256)
void agg_x_kernel(const int* __restrict__ rowptr, const int* __restrict__ csr_src,
                  const float* __restrict__ dinv, const float* __restrict__ x8,
                  float* __restrict__ aggx, int n_nodes) {
  int gid = blockIdx.x * TPB + threadIdx.x;
  int node = gid >> 3;
  int f = gid & 7;
  if (node >= n_nodes) return;
  float dn = dinv[node];
  float acc = x8[(size_t)node * 8 + f] * dn * dn;
  int beg = rowptr[node], end = rowptr[node + 1];
  for (int i = beg; i < end; ++i) {
    int s = csr_src[i];
    acc = fmaf(x8[(size_t)s * 8 + f], dinv[s] * dn, acc);
  }
  aggx[(size_t)node * 8 + f] = acc;
}

// g1 = A_hat @ h1 with h1s prescaled by dinv (bf16):
// g1[n] = dinv[n] * ( h1s[n] + sum_{s in N(n)} h1s[s] )
// 4 edges per wave: quarter q handles edges beg+q, beg+q+4, ... (x2 unrolled);
// 16 lanes x uint4 (8 bf16) cover the 256B row -> 8 outstanding gathers/wave.
__global__ __launch_bounds__(256)
void gather4_kernel(const int* __restrict__ rowptr, const int* __restrict__ csr_src,
                    const float* __restrict__ dinv, const uint4* __restrict__ h1s,
                    uint4* __restrict__ g1, int n_nodes) {
  int wid = (blockIdx.x * TPB + threadIdx.x) >> 6;
  if (wid >= n_nodes) return;
  int lane = threadIdx.x & 63;
  int qtr = lane >> 4;
  int l = lane & 15;          // uint4 index within row (16 per row)
  float acc[8];
  #pragma unroll
  for (int j = 0; j < 8; ++j) acc[j] = 0.0f;
  auto addv = [&](uint4 v) {
    unsigned int u[4] = {v.x, v.y, v.z, v.w};
    #pragma unroll
    for (int p = 0; p < 4; ++p) {
      acc[2 * p]     += __uint_as_float(u[p] << 16);
      acc[2 * p + 1] += __uint_as_float(u[p] & 0xffff0000u);
    }
  };
  if (qtr == 0) addv(h1s[(size_t)wid * 16 + l]);  // self term
  int beg = rowptr[wid], end = rowptr[wid + 1];
  int i = beg + qtr;
  for (; i + 4 < end; i += 8) {
    int s0 = csr_src[i];
    int s1 = csr_src[i + 4];
    uint4 v0 = h1s[(size_t)s0 * 16 + l];
    uint4 v1 = h1s[(size_t)s1 * 16 + l];
    addv(v0);
    addv(v1);
  }
  if (i < end) addv(h1s[(size_t)csr_src[i] * 16 + l]);
  #pragma unroll
  for (int j = 0; j < 8; ++j) {
    acc[j] += __shfl_xor(acc[j], 16, 64);
    acc[j] += __shfl_xor(acc[j], 32, 64);
  }
  if (qtr == 0) {
    float dn = dinv[wid];
    unsigned int w[4];
    #pragma unroll
    for (int p = 0; p < 4; ++p) {
      unsigned int lo = (unsigned int)(unsigned short)f2bf(acc[2 * p] * dn);
      unsigned int hi = (unsigned int)(unsigned short)f2bf(acc[2 * p + 1] * dn);
      w[p] = lo | (hi << 16);
    }
    uint4 o; o.x = w[0]; o.y = w[1]; o.z = w[2]; o.w = w[3];
    g1[(size_t)wid * 16 + l] = o;
  }
}

// Register-tiled SGEMM: out[row][j] = sum_k in[row][k]*W[k][j] (+bias)(+relu)
// OB: bf16 output; IB: bf16 input; SC: multiply output by scale[row] (after relu)
template<int K, int CO, bool OB, bool IB, bool SC>
__global__ __launch_bounds__(256)
void mm_tiled(const void* __restrict__ inv, const float* __restrict__ W,
              const float* __restrict__ bias, const float* __restrict__ scale,
              void* __restrict__ outv, int n_rows, int do_relu) {
  constexpr int BM = 64;
  constexpr int BK = (K % 32 == 0) ? 32 : K;
  constexpr int SS = BK + 1 + (BK & 1);
  constexpr int TM = 4;
  constexpr int TN = CO / 16;
  __shared__ float s_in[BM][SS];
  __shared__ float s_w[BK][CO];
  const int tid = threadIdx.x;
  const int base = blockIdx.x * BM;
  const int tr = tid >> 4;
  const int tc = tid & 15;

  float acc[TM][TN];
  #pragma unroll
  for (int m = 0; m < TM; ++m)
    #pragma unroll
    for (int n = 0; n < TN; ++n) acc[m][n] = 0.0f;

  for (int kb = 0; kb < K; kb += BK) {
    if constexpr (IB) {
      const unsigned short* inb = (const unsigned short*)inv;
      constexpr int C4 = BK / 4;        // uint2 (4 bf16) chunks per row
      constexpr int F4 = BM * C4;
      #pragma unroll
      for (int t = tid; t < F4; t += TPB) {
        int r = t / C4, c4 = t % C4;
        int row = base + r;
        uint2 v = make_uint2(0u, 0u);
        if (row < n_rows) v = *(const uint2*)(inb + (size_t)row * K + kb + c4 * 4);
        s_in[r][c4 * 4 + 0] = __uint_as_float(v.x << 16);
        s_in[r][c4 * 4 + 1] = __uint_as_float(v.x & 0xffff0000u);
        s_in[r][c4 * 4 + 2] = __uint_as_float(v.y << 16);
        s_in[r][c4 * 4 + 3] = __uint_as_float(v.y & 0xffff0000u);
      }
    } else if constexpr (BK % 4 == 0) {
      const float* in = (const float*)inv;
      constexpr int F4 = BM * (BK / 4);
      #pragma unroll
      for (int t = tid; t < F4; t += TPB) {
        int r = t / (BK / 4), c4 = t % (BK / 4);
        int row = base + r;
        float4 v = make_float4(0.f, 0.f, 0.f, 0.f);
        if (row < n_rows) v = *(const float4*)(in + (size_t)row * K + kb + c4 * 4);
        s_in[r][c4 * 4 + 0] = v.x;
        s_in[r][c4 * 4 + 1] = v.y;
        s_in[r][c4 * 4 + 2] = v.z;
        s_in[r][c4 * 4 + 3] = v.w;
      }
    } else {
      const float* in = (const float*)inv;
      for (int t = tid; t < BM * BK; t += TPB) {
        int r = t / BK, c = t % BK;
        int row = base + r;
        s_in[r][c] = (row < n_rows) ? in[(size_t)row * K + kb + c] : 0.0f;
      }
    }
    {
      constexpr int WF4 = BK * CO / 4;
      #pragma unroll
      for (int t = tid; t < WF4; t += TPB)
        *(float4*)(&s_w[0][0] + t * 4) = *(const float4*)(W + (size_t)kb * CO + t * 4);
    }
    __syncthreads();

    #pragma unroll
    for (int kk = 0; kk < BK; ++kk) {
      float a[TM], b[TN];
      #pragma unroll
      for (int m = 0; m < TM; ++m) a[m] = s_in[tr * TM + m][kk];
      #pragma unroll
      for (int n = 0; n < TN; ++n) b[n] = s_w[kk][tc + 16 * n];
      #pragma unroll
      for (int m = 0; m < TM; ++m)
        #pragma unroll
        for (int n = 0; n < TN; ++n) acc[m][n] = fmaf(a[m], b[n], acc[m][n]);
    }
    __syncthreads();
  }

  #pragma unroll
  for (int m = 0; m < TM; ++m) {
    int row = base + tr * TM + m;
    if (row < n_rows) {
      float sc = 1.0f;
      if constexpr (SC) sc = scale[row];
      #pragma unroll
      for (int n = 0; n < TN; ++n) {
        int j = tc + 16 * n;
        float v = acc[m][n] + (bias ? bias[j] : 0.0f);
        if (do_relu) v = fmaxf(v, 0.0f);
        if constexpr (SC) v *= sc;
        if constexpr (OB)
          ((unsigned short*)outv)[(size_t)row * CO + j] = (unsigned short)f2bf(v);
        else
          ((float*)outv)[(size_t)row * CO + j] = v;
      }
    }
  }
}

// MFMA decoder: 16 queries per wave-tile. (layouts guide-verified)
__global__ __launch_bounds__(256)
void decoder_mfma_kernel(const int* __restrict__ qsrc, const int* __restrict__ qdst,
                         const unsigned short* __restrict__ atab,
                         const unsigned short* __restrict__ btab,
                         const float* __restrict__ Wd2, const float* __restrict__ bd2,
                         const float* __restrict__ Wd3, const float* __restrict__ bd3,
                         float* __restrict__ out, int n_query) {
  const int lane = threadIdx.x & 63;
  const int col = lane & 15;
  const int sub = lane >> 4;

  bf16x8 bfrag[4][4];
  #pragma unroll
  for (int ks = 0; ks < 4; ++ks)
    #pragma unroll
    for (int nt = 0; nt < 4; ++nt) {
      bf16x8 f;
      #pragma unroll
      for (int j = 0; j < 8; ++j) {
        int k = ks * 32 + sub * 8 + j;
        int n = nt * 16 + col;
        f[j] = f2bf(Wd2[k * 64 + n]);
      }
      bfrag[ks][nt] = f;
    }
  float bd2v[4], wd3v[4];
  #pragma unroll
  for (int nt = 0; nt < 4; ++nt) {
    bd2v[nt] = bd2[nt * 16 + col];
    wd3v[nt] = Wd3[nt * 16 + col];
  }
  const float bd3s = bd3[0];

  int wave = (blockIdx.x * TPB + threadIdx.x) >> 6;
  int nwaves = gridDim.x * (TPB / 64);
  int ntiles = (n_query + 15) >> 4;
  for (int t = wave; t < ntiles; t += nwaves) {
    int qb = t << 4;
    int q = qb + col;
    if (q >= n_query) q = n_query - 1;
    int si = qsrc[q], di = qdst[q];
    const bf16x8* ar = (const bf16x8*)(atab + (size_t)si * 128);
    const bf16x8* br = (const bf16x8*)(btab + (size_t)di * 128);
    bf16x8 afrag[4];
    #pragma unroll
    for (int ks = 0; ks < 4; ++ks) {
      bf16x8 av = ar[ks * 4 + sub];
      bf16x8 bv = br[ks * 4 + sub];
      bf16x8 d;
      #pragma unroll
      for (int j = 0; j < 8; ++j)
        d[j] = f2bf(fmaxf(bf2f(av[j]) + bf2f(bv[j]), 0.0f));  // d1 = relu(a+b)
      afrag[ks] = d;
    }
    f32x4 acc[4];
    #pragma unroll
    for (int nt = 0; nt < 4; ++nt) acc[nt] = {0.f, 0.f, 0.f, 0.f};
    #pragma unroll
    for (int ks = 0; ks < 4; ++ks)
      #pragma unroll
      for (int nt = 0; nt < 4; ++nt)
        acc[nt] = __builtin_amdgcn_mfma_f32_16x16x32_bf16(afrag[ks], bfrag[ks][nt], acc[nt], 0, 0, 0);
    float part[4] = {0.f, 0.f, 0.f, 0.f};
    #pragma unroll
    for (int nt = 0; nt < 4; ++nt)
      #pragma unroll
      for (int r = 0; r < 4; ++r) {
        float v = fmaxf(acc[nt][r] + bd2v[nt], 0.0f);
        part[r] = fmaf(v, wd3v[nt], part[r]);
      }
    #pragma unroll
    for (int off = 1; off < 16; off <<= 1)
      #pragma unroll
      for (int r = 0; r < 4; ++r) part[r] += __shfl_xor(part[r], off, 64);
    if (col == 0) {
      int row0 = qb + sub * 4;
      #pragma unroll
      for (int r = 0; r < 4; ++r) {
        int qq = row0 + r;
        if (qq < n_query) out[qq] = 1.0f / (1.0f + __expf(-(part[r] + bd3s)));
      }
    }
  }
}

extern "C" void kernel_launch(void* const* d_in, const int* in_sizes, int n_in,
                              void* d_out, int out_size, void* d_ws, size_t ws_size,
                              hipStream_t stream) {
  const float* x    = (const float*)d_in[0];
  const int*   ei   = (const int*)d_in[1];
  const int*   qe   = (const int*)d_in[2];
  const float* W1   = (const float*)d_in[3];
  const float* b1   = (const float*)d_in[4];
  const float* W2   = (const float*)d_in[5];
  const float* b2   = (const float*)d_in[6];
  const float* Wfc  = (const float*)d_in[7];
  const float* bfc  = (const float*)d_in[8];
  const float* Wd1  = (const float*)d_in[9];
  const float* bd1  = (const float*)d_in[10];
  const float* Wd2  = (const float*)d_in[11];
  const float* bd2  = (const float*)d_in[12];
  const float* Wd3  = (const float*)d_in[13];
  const float* bd3  = (const float*)d_in[14];
  float* out = (float*)d_out;

  const int n_nodes = in_sizes[0] / 7;
  const int n_edges = in_sizes[1] / 2;
  const int n_query = in_sizes[2] / 2;
  const int* e_src = ei;
  const int* e_dst = ei + n_edges;
  const int* q_src = qe;
  const int* q_dst = qe + n_query;

  // ---- workspace layout ----
  char* wp = (char*)d_ws;
  auto take = [&](size_t bytes) { char* p = wp; wp += (bytes + 255) & ~size_t(255); return p; };
  float* dinv    = (float*)take((size_t)n_nodes * 4);
  int*   counts  = (int*)  take((size_t)n_nodes * 4);   // reused as cursor
  int*   rowptr  = (int*)  take((size_t)(n_nodes + 1) * 4);
  int*   bsum    = (int*)  take(512 * 4);
  int*   csr_src = (int*)  take((size_t)n_edges * 4);
  float* x8      = (float*)take((size_t)n_nodes * 8 * 4);
  float* aggx    = (float*)take((size_t)n_nodes * 8 * 4);
  float* W1p     = (float*)take(8 * 128 * 4);
  float* bufP    = (float*)take((size_t)n_nodes * 128 * 4);
  float* bufQ    = (float*)take((size_t)n_nodes * 128 * 4);
  float* bufR    = (float*)take((size_t)n_nodes * 64 * 4);

  const int mm_blocks = cdiv(n_nodes, 64);
  const int node_blocks = cdiv(n_nodes, TPB);
  const int edge_blocks = cdiv(n_edges, TPB);
  const int scan_blocks = cdiv(n_nodes, SCAN_B);

  // ---- CSR build (dst-major) + dinv ----
  zero_int_kernel<<<node_blocks, TPB, 0, stream>>>(counts, n_nodes);
  hist_kernel<<<edge_blocks, TPB, 0, stream>>>(e_dst, counts, n_edges);
  dinv_kernel<<<node_blocks, TPB, 0, stream>>>(counts, dinv, n_nodes);
  scan_block_kernel<<<scan_blocks, SCAN_B, 0, stream>>>(counts, rowptr, bsum, n_nodes);
  scan_carry_kernel<<<1, 128, 0, stream>>>(bsum, scan_blocks);
  scan_add_kernel<<<node_blocks, TPB, 0, stream>>>(rowptr, bsum, n_nodes, n_edges);
  zero_int_kernel<<<node_blocks, TPB, 0, stream>>>(counts, n_nodes);  // -> cursor
  scatter_kernel<<<edge_blocks, TPB, 0, stream>>>(e_src, e_dst, rowptr, counts, csr_src, n_edges);

  // ---- pad x / W1 ----
  pad_x8_kernel<<<cdiv(n_nodes * 8, TPB), TPB, 0, stream>>>(x, x8, n_nodes);
  pad_w1_kernel<<<4, TPB, 0, stream>>>(W1, W1p);

  // ---- layer 1: aggx = A_hat x ; h1s(bf16) = relu(aggx @ W1p + b1) * dinv ----
  agg_x_kernel<<<cdiv(n_nodes * 8, TPB), TPB, 0, stream>>>(rowptr, csr_src, dinv, x8, aggx, n_nodes);
  mm_tiled<8, 128, true, false, true><<<mm_blocks, TPB, 0, stream>>>(aggx, W1p, b1, dinv, bufP, n_nodes, 1);
  // bufP = h1s (bf16, prescaled)

  // ---- layer 2: g1(bf16) = dinv * (A_hat-sum of h1s) ; h2 = relu(g1 @ W2 + b2) ----
  gather4_kernel<<<cdiv(n_nodes * 64, TPB), TPB, 0, stream>>>(rowptr, csr_src, dinv,
                                                              (const uint4*)bufP, (uint4*)bufQ, n_nodes);
  mm_tiled<128, 128, false, true, false><<<mm_blocks, TPB, 0, stream>>>(bufQ, W2, b2, nullptr, bufP, n_nodes, 1);
  // bufP = h2 (f32)

  // ---- encoder fc: z = h2 @ Wfc + bfc ----
  mm_tiled<128, 64, false, false, false><<<mm_blocks, TPB, 0, stream>>>(bufP, Wfc, bfc, nullptr, bufR, n_nodes, 0);

  // ---- decoder tables (bf16): atab = z@Wd1_top + bd1 -> bufQ ; btab = z@Wd1_bot -> bufP ----
  unsigned short* atab = (unsigned short*)bufQ;
  unsigned short* btab = (unsigned short*)bufP;
  mm_tiled<64, 128, true, false, false><<<mm_blocks, TPB, 0, stream>>>(bufR, Wd1, bd1, nullptr, atab, n_nodes, 0);
  mm_tiled<64, 128, true, false, false><<<mm_blocks, TPB, 0, stream>>>(bufR, Wd1 + 64 * 128, nullptr, nullptr, btab, n_nodes, 0);

  // ---- per-query decode (MFMA) ----
  decoder_mfma_kernel<<<2048, TPB, 0, stream>>>(q_src, q_dst, atab, btab, Wd2, bd2, Wd3, bd3, out, n_query);
}